// Round 1
// baseline (8380.679 us; speedup 1.0000x reference)
//
#include <hip/hip_runtime.h>
#include <hip/hip_cooperative_groups.h>

namespace cg = cooperative_groups;

#define T_SEQ 200
#define NB    32
#define NE    300
#define NH    1000
#define NG    4000
#define NK    9
#define HP    1024   // padded hidden (row stride of hs, elements)
#define ES    328    // LDS row stride for embed/W tiles (elements)
#define EPD   320    // padded K for projection MFMA

typedef __attribute__((ext_vector_type(4))) float f32x4;
typedef __attribute__((ext_vector_type(8))) short s16x8;
typedef __attribute__((ext_vector_type(4))) short s16x4;

__device__ __forceinline__ unsigned short f2bf(float f) {
    union { float f; unsigned u; } v; v.f = f;
    unsigned r = v.u + 0x7FFFu + ((v.u >> 16) & 1u);   // RNE
    return (unsigned short)(r >> 16);
}
__device__ __forceinline__ float bf2f(unsigned short h) {
    union { unsigned u; float f; } v; v.u = ((unsigned)h) << 16;
    return v.f;
}

// ---------------------------------------------------------------------------
// Kernel 1: xg[t][j'][b] = (embed(x[t,b]) . W_ih[j]) + b_ih[j] + b_hh[j]  (bf16)
// j' permutation: j' = wg*16 + q*4 + u  <->  j = q*1000 + wg*4 + u
// ---------------------------------------------------------------------------
__global__ __launch_bounds__(256) void proj_kernel(
    const int* __restrict__ x, const float* __restrict__ embed_w,
    const float* __restrict__ W_ih, const float* __restrict__ b_ih,
    const float* __restrict__ b_hh, unsigned short* __restrict__ xg)
{
    __shared__ __align__(16) unsigned short s_emb[NB * ES];
    __shared__ __align__(16) unsigned short s_w[64 * ES];
    const int t   = blockIdx.y;
    const int jt  = blockIdx.x;            // 63 tiles of 64 j'
    const int tid = threadIdx.x;

    for (int idx = tid; idx < NB * EPD; idx += 256) {
        int b = idx / EPD, e = idx - b * EPD;
        float v = 0.f;
        if (e < NE) v = embed_w[(size_t)x[t * NB + b] * NE + e];
        s_emb[b * ES + e] = f2bf(v);
    }
    for (int idx = tid; idx < 64 * EPD; idx += 256) {
        int jr = idx / EPD, e = idx - jr * EPD;
        int jp = jt * 64 + jr;
        float v = 0.f;
        if (jp < NG && e < NE) {
            int q = (jp >> 2) & 3, u = jp & 3, wgi = jp >> 4;
            v = W_ih[(size_t)(q * NH + wgi * 4 + u) * NE + e];
        }
        s_w[jr * ES + e] = f2bf(v);
    }
    __syncthreads();

    const int wv = tid >> 6, lane = tid & 63;
    const int col = lane & 15, quad = lane >> 4;
    f32x4 acc0 = {0.f, 0.f, 0.f, 0.f};
    f32x4 acc1 = {0.f, 0.f, 0.f, 0.f};
#pragma unroll
    for (int k0 = 0; k0 < EPD; k0 += 32) {
        int ko = k0 + quad * 8;
        s16x8 a0 = *(const s16x8*)&s_emb[col * ES + ko];
        s16x8 a1 = *(const s16x8*)&s_emb[(16 + col) * ES + ko];
        s16x8 bb = *(const s16x8*)&s_w[(wv * 16 + col) * ES + ko];
        acc0 = __builtin_amdgcn_mfma_f32_16x16x32_bf16(a0, bb, acc0, 0, 0, 0);
        acc1 = __builtin_amdgcn_mfma_f32_16x16x32_bf16(a1, bb, acc1, 0, 0, 0);
    }
    int jp = jt * 64 + wv * 16 + col;
    if (jp < NG) {
        int q = (jp >> 2) & 3, u = jp & 3, wgi = jp >> 4;
        int j = q * NH + wgi * 4 + u;
        float bias = b_ih[j] + b_hh[j];
        size_t rowoff = ((size_t)t * NG + jp) * NB;
        s16x4 p0, p1;
#pragma unroll
        for (int r = 0; r < 4; ++r) {
            p0[r] = (short)f2bf(acc0[r] + bias);
            p1[r] = (short)f2bf(acc1[r] + bias);
        }
        *(s16x4*)&xg[rowoff + quad * 4]      = p0;
        *(s16x4*)&xg[rowoff + 16 + quad * 4] = p1;
    }
}

// ---------------------------------------------------------------------------
// Kernel 2 (cooperative): LSTM scan. 250 WGs x 128 thr; WG wg owns hidden
// units [4wg,4wg+4). W rows (i,f,g,o per unit) resident in LDS as bf16.
// hs: bf16 [T+1][B][HP]. xg: bf16 [T][j'][B]. c in registers.
// ---------------------------------------------------------------------------
__global__ __launch_bounds__(128, 1) void lstm_kernel(
    const float* __restrict__ W_hh,
    const unsigned short* __restrict__ xg,
    unsigned short* __restrict__ hs)
{
    __shared__ __align__(16) unsigned short s_w[16 * 1032];
    __shared__ float s_g[16 * 33];
    const int wg  = blockIdx.x;
    const int tid = threadIdx.x;
    const int wv = tid >> 6, lane = tid & 63;
    const int col = lane & 15, quad = lane >> 4;

    // stage W_hh rows (n = q*4+u -> row q*1000 + wg*4 + u), zero-pad k>=1000
    for (int idx = tid; idx < 16 * 1032; idx += 128) {
        int n = idx / 1032, k = idx - n * 1032;
        float v = 0.f;
        if (k < NH) {
            int q = n >> 2, u = n & 3;
            v = W_hh[(size_t)(q * NH + wg * 4 + u) * NH + k];
        }
        s_w[idx] = f2bf(v);
    }
    // zero h0 slice (hs[0][b][4wg..4wg+3])
    for (int idx = tid; idx < 4 * NB; idx += 128) {
        int u = idx & 3, b = idx >> 2;
        hs[(size_t)b * HP + wg * 4 + u] = 0;
    }
    __syncthreads();
    cg::grid_group grid = cg::this_grid();
    grid.sync();

    const int u_ep = lane & 3;
    const int b_ep = wv * 16 + (lane >> 2);
    float c_val = 0.f;

    for (int t = 0; t < T_SEQ; ++t) {
        const unsigned short* hprev = hs + (size_t)t * NB * HP;
        f32x4 acc = {0.f, 0.f, 0.f, 0.f};
#pragma unroll 8
        for (int kc = 0; kc < 32; ++kc) {
            int ko = kc * 32 + quad * 8;
            s16x8 a  = *(const s16x8*)&hprev[(size_t)(wv * 16 + col) * HP + ko];
            s16x8 bb = *(const s16x8*)&s_w[col * 1032 + ko];
            acc = __builtin_amdgcn_mfma_f32_16x16x32_bf16(a, bb, acc, 0, 0, 0);
        }
        // add input-gate contribution; lane holds C[b=wv*16+quad*4+r][n=col]
        const s16x4 xv = *(const s16x4*)&xg[((size_t)t * NG + wg * 16 + col) * NB
                                           + wv * 16 + quad * 4];
#pragma unroll
        for (int r = 0; r < 4; ++r) {
            float g = acc[r] + bf2f((unsigned short)xv[r]);
            s_g[col * 33 + wv * 16 + quad * 4 + r] = g;
        }
        __syncthreads();
        {
            float gi = s_g[(u_ep)      * 33 + b_ep];
            float gf = s_g[(4 + u_ep)  * 33 + b_ep];
            float gg = s_g[(8 + u_ep)  * 33 + b_ep];
            float go = s_g[(12 + u_ep) * 33 + b_ep];
            float si = 1.f / (1.f + __expf(-gi));
            float sf = 1.f / (1.f + __expf(-gf));
            float so = 1.f / (1.f + __expf(-go));
            c_val = sf * c_val + si * tanhf(gg);
            float h = so * tanhf(c_val);
            hs[((size_t)(t + 1) * NB + b_ep) * HP + wg * 4 + u_ep] = f2bf(h);
        }
        grid.sync();
    }
}

// ---------------------------------------------------------------------------
// Kernel 3: tag_space + log_softmax over BATCH axis -> emissions[t][b][k] f32
// ---------------------------------------------------------------------------
__global__ __launch_bounds__(320) void tag_kernel(
    const unsigned short* __restrict__ hs, const float* __restrict__ lin_w,
    const float* __restrict__ lin_b, float* __restrict__ em)
{
    __shared__ float s_lin[NH * NK];
    __shared__ float s_ts[NB * NK];
    __shared__ float s_lse[NK];
    const int t = blockIdx.x;
    const int tid = threadIdx.x;
    for (int idx = tid; idx < NH * NK; idx += 320) {
        int e = idx / NK, k = idx - e * NK;
        s_lin[idx] = lin_w[(size_t)k * NH + e];
    }
    __syncthreads();
    if (tid < NB * NK) {
        int b = tid / NK, k = tid - b * NK;
        const unsigned short* hrow = hs + ((size_t)(t + 1) * NB + b) * HP;
        float acc = lin_b[k];
#pragma unroll 4
        for (int e = 0; e < NH; ++e)
            acc += bf2f(hrow[e]) * s_lin[e * NK + k];
        s_ts[b * NK + k] = acc;
    }
    __syncthreads();
    if (tid < NK) {
        float m = -1e30f;
        for (int b = 0; b < NB; ++b) m = fmaxf(m, s_ts[b * NK + tid]);
        float s = 0.f;
        for (int b = 0; b < NB; ++b) s += __expf(s_ts[b * NK + tid] - m);
        s_lse[tid] = m + __logf(s);
    }
    __syncthreads();
    if (tid < NB * NK) {
        int b = tid / NK, k = tid - b * NK;
        em[((size_t)t * NB + b) * NK + k] = s_ts[b * NK + k] - s_lse[k];
    }
}

// ---------------------------------------------------------------------------
// Kernel 4: CRF numerator + alpha recursion + final reduction -> out[0]
// ---------------------------------------------------------------------------
__global__ __launch_bounds__(320) void crf_kernel(
    const int* __restrict__ y, const float* __restrict__ em,
    const float* __restrict__ start_trans, const float* __restrict__ end_trans,
    const float* __restrict__ trans, float* __restrict__ out)
{
    __shared__ float s_trans[NK * NK];
    __shared__ float s_alpha[NB * NK];
    __shared__ float s_red[NB];
    const int tid = threadIdx.x;
    if (tid < NK * NK) s_trans[tid] = trans[tid];
    __syncthreads();

    float num = 0.f;
    if (tid < NB) {
        int b = tid;
        int yp = y[b];
        num = start_trans[yp] + em[(size_t)b * NK + yp];
        for (int t = 1; t < T_SEQ; ++t) {
            int yc = y[t * NB + b];
            num += s_trans[yp * NK + yc] + em[((size_t)t * NB + b) * NK + yc];
            yp = yc;
        }
        num += end_trans[yp];
    }

    const int b = tid / NK, k = tid - (tid / NK) * NK;
    if (tid < NB * NK)
        s_alpha[tid] = start_trans[k] + em[(size_t)b * NK + k];
    __syncthreads();

    for (int t = 1; t < T_SEQ; ++t) {
        float nv = 0.f;
        if (tid < NB * NK) {
            float m = -1e30f;
#pragma unroll
            for (int i = 0; i < NK; ++i)
                m = fmaxf(m, s_alpha[b * NK + i] + s_trans[i * NK + k]);
            float s = 0.f;
#pragma unroll
            for (int i = 0; i < NK; ++i)
                s += __expf(s_alpha[b * NK + i] + s_trans[i * NK + k] - m);
            nv = em[((size_t)t * NB + b) * NK + k] + m + __logf(s);
        }
        __syncthreads();
        if (tid < NB * NK) s_alpha[tid] = nv;
        __syncthreads();
    }

    if (tid < NB) {
        float m = -1e30f;
        for (int k2 = 0; k2 < NK; ++k2)
            m = fmaxf(m, s_alpha[tid * NK + k2] + end_trans[k2]);
        float s = 0.f;
        for (int k2 = 0; k2 < NK; ++k2)
            s += __expf(s_alpha[tid * NK + k2] + end_trans[k2] - m);
        s_red[tid] = num - (m + __logf(s));
    }
    __syncthreads();
    if (tid == 0) {
        float tot = 0.f;
        for (int i = 0; i < NB; ++i) tot += s_red[i];
        out[0] = tot;
    }
}

// ---------------------------------------------------------------------------
extern "C" void kernel_launch(void* const* d_in, const int* in_sizes, int n_in,
                              void* d_out, int out_size, void* d_ws, size_t ws_size,
                              hipStream_t stream)
{
    const int*   x           = (const int*)d_in[0];
    const int*   y           = (const int*)d_in[1];
    const float* embed_w     = (const float*)d_in[2];
    const float* W_ih        = (const float*)d_in[3];
    const float* W_hh        = (const float*)d_in[4];
    const float* b_ih        = (const float*)d_in[5];
    const float* b_hh        = (const float*)d_in[6];
    const float* lin_w       = (const float*)d_in[7];
    const float* lin_b       = (const float*)d_in[8];
    const float* start_trans = (const float*)d_in[9];
    const float* end_trans   = (const float*)d_in[10];
    const float* trans       = (const float*)d_in[11];
    float* out = (float*)d_out;

    char* ws = (char*)d_ws;
    unsigned short* xg = (unsigned short*)ws;                      // 200*4000*32*2 = 51,200,000 B
    unsigned short* hs = (unsigned short*)(ws + 51200000);         // 201*32*1024*2 = 13,172,736 B
    float*          em = (float*)(ws + 51200000 + 13172736);       // 200*32*9*4   =    230,400 B

    proj_kernel<<<dim3(63, T_SEQ), 256, 0, stream>>>(x, embed_w, W_ih, b_ih, b_hh, xg);

    const float* a0 = W_hh;
    const unsigned short* a1 = xg;
    unsigned short* a2 = hs;
    void* args[] = { (void*)&a0, (void*)&a1, (void*)&a2 };
    hipLaunchCooperativeKernel((const void*)lstm_kernel, dim3(250), dim3(128),
                               args, 0, stream);

    tag_kernel<<<dim3(T_SEQ), 320, 0, stream>>>(hs, lin_w, lin_b, em);
    crf_kernel<<<dim3(1), 320, 0, stream>>>(y, em, start_trans, end_trans, trans, out);
}

// Round 2
// 2754.481 us; speedup vs baseline: 3.0426x; 3.0426x over previous
//
#include <hip/hip_runtime.h>

#define T_SEQ 200
#define NB    32
#define NE    300
#define NH    1000
#define NK    9
#define HP    1024          // padded hidden stride (elements)
#define NJ    4032          // xg rows per t: 4 gates * 1008 padded units
#define RW    1008          // padded units
#define EPD   320           // padded embed K
#define WS_LD 1032          // LDS W row stride (2-way-free bank pattern)

typedef __attribute__((ext_vector_type(4))) float f32x4;
typedef __attribute__((ext_vector_type(8))) short s16x8;
typedef __attribute__((ext_vector_type(4))) short s16x4;

__device__ __forceinline__ unsigned short f2bf(float f) {
    union { float f; unsigned u; } v; v.f = f;
    unsigned r = v.u + 0x7FFFu + ((v.u >> 16) & 1u);   // RNE
    return (unsigned short)(r >> 16);
}
__device__ __forceinline__ float bf2f(unsigned short h) {
    union { unsigned u; float f; } v; v.u = ((unsigned)h) << 16;
    return v.f;
}
__device__ __forceinline__ float ftanh(float x) {
    float e = __expf(fminf(2.f * x, 80.f));
    return (e - 1.f) / (e + 1.f);
}
__device__ __forceinline__ float fsig(float x) {
    return 1.f / (1.f + __expf(-x));
}

// ---------------------------------------------------------------------------
// prep_emb: gather+convert embeds -> bf16 [t*32+b][320]; block 0 zeroes ctr
// ---------------------------------------------------------------------------
__global__ __launch_bounds__(256) void prep_emb(
    const int* __restrict__ x, const float* __restrict__ embed_w,
    unsigned short* __restrict__ emb_bf, unsigned* __restrict__ ctr)
{
    const int t = blockIdx.x, tid = threadIdx.x;
    if (blockIdx.x == 0 && tid == 0) ctr[0] = 0;
    for (int idx = tid; idx < NB * EPD; idx += 256) {
        int b = idx / EPD, e = idx - b * EPD;
        float v = (e < NE) ? embed_w[(size_t)x[t * NB + b] * NE + e] : 0.f;
        emb_bf[((size_t)t * NB + b) * EPD + e] = f2bf(v);
    }
}

// ---------------------------------------------------------------------------
// prep_w: W_ih -> bf16 [j'][320] with j' = q*1008+m; also bias[j'] = b_ih+b_hh
// ---------------------------------------------------------------------------
__global__ __launch_bounds__(256) void prep_w(
    const float* __restrict__ W_ih, const float* __restrict__ b_ih,
    const float* __restrict__ b_hh, unsigned short* __restrict__ wih_bf,
    float* __restrict__ biasg)
{
    const int wgi = blockIdx.x, tid = threadIdx.x;   // 63 blocks x 64 rows
    for (int idx = tid; idx < 64 * EPD; idx += 256) {
        int jr = idx / EPD, e = idx - jr * EPD;
        int jp = wgi * 64 + jr;
        int q = jp / RW, m = jp - q * RW;
        float v = (m < NH && e < NE) ? W_ih[(size_t)(q * NH + m) * NE + e] : 0.f;
        wih_bf[(size_t)jp * EPD + e] = f2bf(v);
    }
    if (tid < 64) {
        int jp = wgi * 64 + tid;
        int q = jp / RW, m = jp - q * RW;
        biasg[jp] = (m < NH) ? (b_ih[q * NH + m] + b_hh[q * NH + m]) : 0.f;
    }
}

// ---------------------------------------------------------------------------
// proj: xg[t][j'][b] = emb . W_ih^T + bias   (pure MFMA, no LDS)
// ---------------------------------------------------------------------------
__global__ __launch_bounds__(256) void proj_kernel(
    const unsigned short* __restrict__ emb_bf,
    const unsigned short* __restrict__ wih_bf,
    const float* __restrict__ biasg, unsigned short* __restrict__ xg)
{
    const int jt = blockIdx.x, t = blockIdx.y, tid = threadIdx.x;
    const int w = tid >> 6, lane = tid & 63;
    const int col = lane & 15, quad = lane >> 4;

    const unsigned short* eb = emb_bf + (size_t)t * NB * EPD;
    const unsigned short* wb = wih_bf + (size_t)(jt * 64 + w * 16 + col) * EPD;
    const unsigned short* ea0 = eb + (size_t)col * EPD;
    const unsigned short* ea1 = eb + (size_t)(16 + col) * EPD;

    f32x4 acc0 = {0.f, 0.f, 0.f, 0.f};
    f32x4 acc1 = {0.f, 0.f, 0.f, 0.f};
#pragma unroll
    for (int kc = 0; kc < EPD / 32; ++kc) {
        int ko = kc * 32 + quad * 8;
        s16x8 a0 = *(const s16x8*)&ea0[ko];
        s16x8 a1 = *(const s16x8*)&ea1[ko];
        s16x8 bb = *(const s16x8*)&wb[ko];
        acc0 = __builtin_amdgcn_mfma_f32_16x16x32_bf16(a0, bb, acc0, 0, 0, 0);
        acc1 = __builtin_amdgcn_mfma_f32_16x16x32_bf16(a1, bb, acc1, 0, 0, 0);
    }
    const int jp = jt * 64 + w * 16 + col;
    const float bi = biasg[jp];
    size_t base = ((size_t)t * NJ + jp) * NB;
    s16x4 p0, p1;
#pragma unroll
    for (int r = 0; r < 4; ++r) {
        p0[r] = (short)f2bf(acc0[r] + bi);
        p1[r] = (short)f2bf(acc1[r] + bi);
    }
    *(s16x4*)&xg[base + quad * 4]      = p0;
    *(s16x4*)&xg[base + 16 + quad * 4] = p1;
}

// ---------------------------------------------------------------------------
// custom grid barrier: tid0 arrives (release), spins (acquire), s_barrier
// ---------------------------------------------------------------------------
__device__ __forceinline__ void gbar(unsigned* ctr, unsigned target) {
    __syncthreads();   // drain all WG stores (vmcnt) before publishing
    if (threadIdx.x == 0) {
        __hip_atomic_fetch_add(ctr, 1u, __ATOMIC_RELEASE, __HIP_MEMORY_SCOPE_AGENT);
        while (__hip_atomic_load(ctr, __ATOMIC_ACQUIRE, __HIP_MEMORY_SCOPE_AGENT) < target) {
            __builtin_amdgcn_s_sleep(1);
        }
    }
    __syncthreads();
}

// ---------------------------------------------------------------------------
// lstm (cooperative): 63 WGs x 256 thr. WG wg owns units [16wg,16wg+16).
// Wave w: batch-half bh=w&1, gate pair q0=2*(w>>1), q1=q0+1.
// W_hh (64 rows x 1024) bf16 in LDS. Custom barrier per step.
// ---------------------------------------------------------------------------
__global__ __launch_bounds__(256, 1) void lstm_kernel(
    const float* __restrict__ W_hh,
    const unsigned short* __restrict__ xg,
    unsigned short* __restrict__ hs,
    unsigned* __restrict__ ctr)
{
    __shared__ __align__(16) unsigned short s_w[64 * WS_LD];   // 132,096 B
    __shared__ float s_g[64 * 36];                             //   9,216 B

    const int wg = blockIdx.x, tid = threadIdx.x;
    const int w = tid >> 6, lane = tid & 63;
    const int col = lane & 15, quad = lane >> 4;
    const int bh = w & 1, q0 = (w >> 1) * 2, q1 = q0 + 1;

    // stage W_hh rows -> LDS bf16 (row r = q*16+n -> W_hh[q*1000 + wg*16+n])
    for (int idx = tid; idx < 64 * WS_LD; idx += 256) {
        int r = idx / WS_LD, k = idx - r * WS_LD;
        int q = r >> 4, m = wg * 16 + (r & 15);
        float v = (k < NH && m < NH) ? W_hh[(size_t)(q * NH + m) * NH + k] : 0.f;
        s_w[idx] = f2bf(v);
    }
    // zero h0 slice
    for (int idx = tid; idx < 512; idx += 256) {
        int b = idx >> 4, n = idx & 15;
        hs[(size_t)b * HP + wg * 16 + n] = 0;
    }
    if (wg == 62) {
        for (int idx = tid; idx < 512; idx += 256) {
            int b = idx >> 4, n = idx & 15;
            hs[(size_t)b * HP + 1008 + n] = 0;
        }
    }
    unsigned tgt = 63;
    gbar(ctr, tgt);

    const unsigned short* wb0 = s_w + (size_t)(q0 * 16 + col) * WS_LD;
    const unsigned short* wb1 = s_w + (size_t)(q1 * 16 + col) * WS_LD;
    const int u_ep = tid >> 5;          // 0..7  (and +8 for second pair)
    const int b_ep = tid & 31;
    float c0 = 0.f, c1 = 0.f;

    for (int t = 0; t < T_SEQ; ++t) {
        const unsigned short* hp = hs + (size_t)t * NB * HP + (size_t)(bh * 16 + col) * HP;
        f32x4 A0 = {0.f, 0.f, 0.f, 0.f};
        f32x4 A1 = {0.f, 0.f, 0.f, 0.f};
#pragma unroll 8
        for (int kc = 0; kc < 32; ++kc) {
            int ko = kc * 32 + quad * 8;
            s16x8 a  = *(const s16x8*)&hp[ko];
            s16x8 b0 = *(const s16x8*)&wb0[ko];
            s16x8 b1 = *(const s16x8*)&wb1[ko];
            A0 = __builtin_amdgcn_mfma_f32_16x16x32_bf16(a, b0, A0, 0, 0, 0);
            A1 = __builtin_amdgcn_mfma_f32_16x16x32_bf16(a, b1, A1, 0, 0, 0);
        }
        // add input-gate contribution, scatter to s_g[gate_row][b]
        const s16x4 x0 = *(const s16x4*)&xg[((size_t)t * NJ + q0 * RW + wg * 16 + col) * NB
                                           + bh * 16 + quad * 4];
        const s16x4 x1 = *(const s16x4*)&xg[((size_t)t * NJ + q1 * RW + wg * 16 + col) * NB
                                           + bh * 16 + quad * 4];
#pragma unroll
        for (int r = 0; r < 4; ++r) {
            s_g[(q0 * 16 + col) * 36 + bh * 16 + quad * 4 + r] = A0[r] + bf2f((unsigned short)x0[r]);
            s_g[(q1 * 16 + col) * 36 + bh * 16 + quad * 4 + r] = A1[r] + bf2f((unsigned short)x1[r]);
        }
        __syncthreads();
        // epilogue: 512 (u,b) pairs, 2 per thread; c-state in registers
        {
            float gi = s_g[(0 * 16 + u_ep) * 36 + b_ep];
            float gf = s_g[(1 * 16 + u_ep) * 36 + b_ep];
            float gg = s_g[(2 * 16 + u_ep) * 36 + b_ep];
            float go = s_g[(3 * 16 + u_ep) * 36 + b_ep];
            c0 = fsig(gf) * c0 + fsig(gi) * ftanh(gg);
            float h = fsig(go) * ftanh(c0);
            hs[((size_t)(t + 1) * NB + b_ep) * HP + wg * 16 + u_ep] = f2bf(h);
        }
        {
            int u2 = u_ep + 8;
            float gi = s_g[(0 * 16 + u2) * 36 + b_ep];
            float gf = s_g[(1 * 16 + u2) * 36 + b_ep];
            float gg = s_g[(2 * 16 + u2) * 36 + b_ep];
            float go = s_g[(3 * 16 + u2) * 36 + b_ep];
            c1 = fsig(gf) * c1 + fsig(gi) * ftanh(gg);
            float h = fsig(go) * ftanh(c1);
            hs[((size_t)(t + 1) * NB + b_ep) * HP + wg * 16 + u2] = f2bf(h);
        }
        tgt += 63;
        if (t < T_SEQ - 1) gbar(ctr, tgt);
    }
}

// ---------------------------------------------------------------------------
// tag_kernel: tag_space + log_softmax over BATCH axis -> em[t][b][k] (f32)
// ---------------------------------------------------------------------------
__global__ __launch_bounds__(320) void tag_kernel(
    const unsigned short* __restrict__ hs, const float* __restrict__ lin_w,
    const float* __restrict__ lin_b, float* __restrict__ em)
{
    __shared__ float s_lin[NH * NK];
    __shared__ float s_ts[NB * NK];
    __shared__ float s_lse[NK];
    const int t = blockIdx.x, tid = threadIdx.x;
    for (int idx = tid; idx < NH * NK; idx += 320) {
        int e = idx / NK, k = idx - e * NK;
        s_lin[idx] = lin_w[(size_t)k * NH + e];
    }
    __syncthreads();
    if (tid < NB * NK) {
        int b = tid / NK, k = tid - b * NK;
        const unsigned short* hrow = hs + ((size_t)(t + 1) * NB + b) * HP;
        float acc = lin_b[k];
#pragma unroll 4
        for (int e = 0; e < NH; ++e)
            acc += bf2f(hrow[e]) * s_lin[e * NK + k];
        s_ts[b * NK + k] = acc;
    }
    __syncthreads();
    if (tid < NK) {
        float m = -1e30f;
        for (int b = 0; b < NB; ++b) m = fmaxf(m, s_ts[b * NK + tid]);
        float s = 0.f;
        for (int b = 0; b < NB; ++b) s += __expf(s_ts[b * NK + tid] - m);
        s_lse[tid] = m + __logf(s);
    }
    __syncthreads();
    if (tid < NB * NK) {
        int b = tid / NK, k = tid - b * NK;
        em[((size_t)t * NB + b) * NK + k] = s_ts[b * NK + k] - s_lse[k];
    }
}

// ---------------------------------------------------------------------------
// crf_kernel: numerator + alpha recursion + reduction -> out[0]
// ---------------------------------------------------------------------------
__global__ __launch_bounds__(320) void crf_kernel(
    const int* __restrict__ y, const float* __restrict__ em,
    const float* __restrict__ start_trans, const float* __restrict__ end_trans,
    const float* __restrict__ trans, float* __restrict__ out)
{
    __shared__ float s_trans[NK * NK];
    __shared__ float s_alpha[NB * NK];
    __shared__ float s_red[NB];
    const int tid = threadIdx.x;
    if (tid < NK * NK) s_trans[tid] = trans[tid];
    __syncthreads();

    float num = 0.f;
    if (tid < NB) {
        int b = tid, yp = y[b];
        num = start_trans[yp] + em[(size_t)b * NK + yp];
        for (int t = 1; t < T_SEQ; ++t) {
            int yc = y[t * NB + b];
            num += s_trans[yp * NK + yc] + em[((size_t)t * NB + b) * NK + yc];
            yp = yc;
        }
        num += end_trans[yp];
    }

    const int b = tid / NK, k = tid - (tid / NK) * NK;
    if (tid < NB * NK)
        s_alpha[tid] = start_trans[k] + em[(size_t)b * NK + k];
    __syncthreads();

    for (int t = 1; t < T_SEQ; ++t) {
        float nv = 0.f;
        if (tid < NB * NK) {
            float m = -1e30f;
#pragma unroll
            for (int i = 0; i < NK; ++i)
                m = fmaxf(m, s_alpha[b * NK + i] + s_trans[i * NK + k]);
            float s = 0.f;
#pragma unroll
            for (int i = 0; i < NK; ++i)
                s += __expf(s_alpha[b * NK + i] + s_trans[i * NK + k] - m);
            nv = em[((size_t)t * NB + b) * NK + k] + m + __logf(s);
        }
        __syncthreads();
        if (tid < NB * NK) s_alpha[tid] = nv;
        __syncthreads();
    }

    if (tid < NB) {
        float m = -1e30f;
        for (int k2 = 0; k2 < NK; ++k2)
            m = fmaxf(m, s_alpha[tid * NK + k2] + end_trans[k2]);
        float s = 0.f;
        for (int k2 = 0; k2 < NK; ++k2)
            s += __expf(s_alpha[tid * NK + k2] + end_trans[k2] - m);
        s_red[tid] = num - (m + __logf(s));
    }
    __syncthreads();
    if (tid == 0) {
        float tot = 0.f;
        for (int i = 0; i < NB; ++i) tot += s_red[i];
        out[0] = tot;
    }
}

// ---------------------------------------------------------------------------
extern "C" void kernel_launch(void* const* d_in, const int* in_sizes, int n_in,
                              void* d_out, int out_size, void* d_ws, size_t ws_size,
                              hipStream_t stream)
{
    const int*   x           = (const int*)d_in[0];
    const int*   y           = (const int*)d_in[1];
    const float* embed_w     = (const float*)d_in[2];
    const float* W_ih        = (const float*)d_in[3];
    const float* W_hh        = (const float*)d_in[4];
    const float* b_ih        = (const float*)d_in[5];
    const float* b_hh        = (const float*)d_in[6];
    const float* lin_w       = (const float*)d_in[7];
    const float* lin_b       = (const float*)d_in[8];
    const float* start_trans = (const float*)d_in[9];
    const float* end_trans   = (const float*)d_in[10];
    const float* trans       = (const float*)d_in[11];
    float* out = (float*)d_out;

    char* ws = (char*)d_ws;
    unsigned short* xg     = (unsigned short*)(ws);               // 51,609,600 B
    unsigned short* hs     = (unsigned short*)(ws + 51609600);    // 13,172,736 B
    float*          em     = (float*)(ws + 64782336);             //    230,400 B
    unsigned*       ctr    = (unsigned*)(ws + 65012736);          //        256 B
    unsigned short* emb_bf = (unsigned short*)(ws + 65012992);    //  4,096,000 B
    unsigned short* wih_bf = (unsigned short*)(ws + 69108992);    //  2,580,480 B
    float*          biasg  = (float*)(ws + 71689472);             //     16,128 B

    prep_emb<<<dim3(T_SEQ), 256, 0, stream>>>(x, embed_w, emb_bf, ctr);
    prep_w<<<dim3(63), 256, 0, stream>>>(W_ih, b_ih, b_hh, wih_bf, biasg);
    proj_kernel<<<dim3(63, T_SEQ), 256, 0, stream>>>(emb_bf, wih_bf, biasg, xg);

    const float* a0 = W_hh;
    const unsigned short* a1 = xg;
    unsigned short* a2 = hs;
    unsigned* a3 = ctr;
    void* args[] = { (void*)&a0, (void*)&a1, (void*)&a2, (void*)&a3 };
    hipLaunchCooperativeKernel((const void*)lstm_kernel, dim3(63), dim3(256),
                               args, 0, stream);

    tag_kernel<<<dim3(T_SEQ), 320, 0, stream>>>(hs, lin_w, lin_b, em);
    crf_kernel<<<dim3(1), 320, 0, stream>>>(y, em, start_trans, end_trans, trans, out);
}

// Round 4
// 2502.118 us; speedup vs baseline: 3.3494x; 1.1009x over previous
//
#include <hip/hip_runtime.h>

#define T_SEQ 200
#define NB    32
#define NE    300
#define NH    1000
#define NK    9
#define HP    1024          // padded hidden stride (elements)
#define NJ    4032          // xg rows per t: 4 gates * 1008 padded units
#define RW    1008          // padded units
#define EPD   320           // padded embed K
#define WS_LD 1032          // LDS W row stride

typedef __attribute__((ext_vector_type(4))) float f32x4;
typedef __attribute__((ext_vector_type(8))) short s16x8;
typedef __attribute__((ext_vector_type(4))) short s16x4;

__device__ __forceinline__ unsigned short f2bf(float f) {
    union { float f; unsigned u; } v; v.f = f;
    unsigned r = v.u + 0x7FFFu + ((v.u >> 16) & 1u);   // RNE
    return (unsigned short)(r >> 16);
}
__device__ __forceinline__ float bf2f(unsigned short h) {
    union { unsigned u; float f; } v; v.u = ((unsigned)h) << 16;
    return v.f;
}
__device__ __forceinline__ float ftanh(float x) {
    float e = __expf(fminf(2.f * x, 80.f));
    return (e - 1.f) / (e + 1.f);
}
__device__ __forceinline__ float fsig(float x) {
    return 1.f / (1.f + __expf(-x));
}

// ---------------------------------------------------------------------------
// prep_emb: gather+convert embeds -> bf16 [t*32+b][320]; block 0 zeroes flags
// ---------------------------------------------------------------------------
__global__ __launch_bounds__(256) void prep_emb(
    const int* __restrict__ x, const float* __restrict__ embed_w,
    unsigned short* __restrict__ emb_bf, unsigned* __restrict__ flags)
{
    const int t = blockIdx.x, tid = threadIdx.x;
    if (blockIdx.x == 0) {
        for (int i = tid; i < 2048; i += 256) flags[i] = 0;
    }
    for (int idx = tid; idx < NB * EPD; idx += 256) {
        int b = idx / EPD, e = idx - b * EPD;
        float v = (e < NE) ? embed_w[(size_t)x[t * NB + b] * NE + e] : 0.f;
        emb_bf[((size_t)t * NB + b) * EPD + e] = f2bf(v);
    }
}

// ---------------------------------------------------------------------------
// prep_w: W_ih -> bf16 [j'][320] with j' = q*1008+m; bias[j'] = b_ih+b_hh
// ---------------------------------------------------------------------------
__global__ __launch_bounds__(256) void prep_w(
    const float* __restrict__ W_ih, const float* __restrict__ b_ih,
    const float* __restrict__ b_hh, unsigned short* __restrict__ wih_bf,
    float* __restrict__ biasg)
{
    const int wgi = blockIdx.x, tid = threadIdx.x;   // 63 blocks x 64 rows
    for (int idx = tid; idx < 64 * EPD; idx += 256) {
        int jr = idx / EPD, e = idx - jr * EPD;
        int jp = wgi * 64 + jr;
        int q = jp / RW, m = jp - q * RW;
        float v = (m < NH && e < NE) ? W_ih[(size_t)(q * NH + m) * NE + e] : 0.f;
        wih_bf[(size_t)jp * EPD + e] = f2bf(v);
    }
    if (tid < 64) {
        int jp = wgi * 64 + tid;
        int q = jp / RW, m = jp - q * RW;
        biasg[jp] = (m < NH) ? (b_ih[q * NH + m] + b_hh[q * NH + m]) : 0.f;
    }
}

// ---------------------------------------------------------------------------
// proj: xg[t][j'][b] = emb . W_ih^T + bias   (pure MFMA, no LDS)
// ---------------------------------------------------------------------------
__global__ __launch_bounds__(256) void proj_kernel(
    const unsigned short* __restrict__ emb_bf,
    const unsigned short* __restrict__ wih_bf,
    const float* __restrict__ biasg, unsigned short* __restrict__ xg)
{
    const int jt = blockIdx.x, t = blockIdx.y, tid = threadIdx.x;
    const int w = tid >> 6, lane = tid & 63;
    const int col = lane & 15, quad = lane >> 4;

    const unsigned short* eb = emb_bf + (size_t)t * NB * EPD;
    const unsigned short* wb = wih_bf + (size_t)(jt * 64 + w * 16 + col) * EPD;
    const unsigned short* ea0 = eb + (size_t)col * EPD;
    const unsigned short* ea1 = eb + (size_t)(16 + col) * EPD;

    f32x4 acc0 = {0.f, 0.f, 0.f, 0.f};
    f32x4 acc1 = {0.f, 0.f, 0.f, 0.f};
#pragma unroll
    for (int kc = 0; kc < EPD / 32; ++kc) {
        int ko = kc * 32 + quad * 8;
        s16x8 a0 = *(const s16x8*)&ea0[ko];
        s16x8 a1 = *(const s16x8*)&ea1[ko];
        s16x8 bb = *(const s16x8*)&wb[ko];
        acc0 = __builtin_amdgcn_mfma_f32_16x16x32_bf16(a0, bb, acc0, 0, 0, 0);
        acc1 = __builtin_amdgcn_mfma_f32_16x16x32_bf16(a1, bb, acc1, 0, 0, 0);
    }
    const int jp = jt * 64 + w * 16 + col;
    const float bi = biasg[jp];
    size_t base = ((size_t)t * NJ + jp) * NB;
    s16x4 p0, p1;
#pragma unroll
    for (int r = 0; r < 4; ++r) {
        p0[r] = (short)f2bf(acc0[r] + bi);
        p1[r] = (short)f2bf(acc1[r] + bi);
    }
    *(s16x4*)&xg[base + quad * 4]      = p0;
    *(s16x4*)&xg[base + 16 + quad * 4] = p1;
}

// ---------------------------------------------------------------------------
// flag-array grid barrier: WG wg publishes flags[wg*32]=phase (release, own
// cacheline); wave 0 polls all 63 slots with ONE lane-parallel relaxed load,
// acquire fence exactly once after success.
// ---------------------------------------------------------------------------
__device__ __forceinline__ void gbar2(unsigned* flags, unsigned phase) {
    __syncthreads();   // all waves' stores issued & vmcnt-drained
    const int tid = threadIdx.x;
    if (tid < 64) {
        if (tid == 0) {
            __builtin_amdgcn_fence(__ATOMIC_RELEASE, "agent");
            __hip_atomic_store(&flags[blockIdx.x * 32], phase,
                               __ATOMIC_RELAXED, __HIP_MEMORY_SCOPE_AGENT);
        }
        bool done;
        do {
            unsigned v = (tid < 63)
                ? __hip_atomic_load(&flags[tid * 32], __ATOMIC_RELAXED,
                                    __HIP_MEMORY_SCOPE_AGENT)
                : phase;
            done = (bool)__all((int)(v >= phase));
            if (!done) __builtin_amdgcn_s_sleep(1);
        } while (!done);
        if (tid == 0)
            __builtin_amdgcn_fence(__ATOMIC_ACQUIRE, "agent");
    }
    __syncthreads();
}

// ---------------------------------------------------------------------------
// lstm (cooperative): 63 WGs x 256 thr. WG wg owns units [16wg,16wg+16).
// Wave w: batch-half bh=w&1, gate pair q0=2*(w>>1), q1=q0+1.
// W_hh (64 rows x 1024) bf16 in LDS. Flag-array barrier per step.
// ---------------------------------------------------------------------------
__global__ __launch_bounds__(256, 1) void lstm_kernel(
    const float* __restrict__ W_hh,
    const unsigned short* __restrict__ xg,
    unsigned short* __restrict__ hs,
    unsigned* __restrict__ flags)
{
    __shared__ __align__(16) unsigned short s_w[64 * WS_LD];   // 132,096 B
    __shared__ float s_g[64 * 36];                             //   9,216 B

    const int wg = blockIdx.x, tid = threadIdx.x;
    const int w = tid >> 6, lane = tid & 63;
    const int col = lane & 15, quad = lane >> 4;
    const int bh = w & 1, q0 = (w >> 1) * 2, q1 = q0 + 1;

    // stage W_hh rows -> LDS bf16 (row r = q*16+n -> W_hh[q*1000 + wg*16+n])
    for (int idx = tid; idx < 64 * WS_LD; idx += 256) {
        int r = idx / WS_LD, k = idx - r * WS_LD;
        int q = r >> 4, m = wg * 16 + (r & 15);
        float v = (k < NH && m < NH) ? W_hh[(size_t)(q * NH + m) * NH + k] : 0.f;
        s_w[idx] = f2bf(v);
    }
    // zero h0 slice
    for (int idx = tid; idx < 512; idx += 256) {
        int b = idx >> 4, n = idx & 15;
        hs[(size_t)b * HP + wg * 16 + n] = 0;
    }
    if (wg == 62) {
        for (int idx = tid; idx < 512; idx += 256) {
            int b = idx >> 4, n = idx & 15;
            hs[(size_t)b * HP + 1008 + n] = 0;
        }
    }
    gbar2(flags, 1u);

    const unsigned short* wb0 = s_w + (size_t)(q0 * 16 + col) * WS_LD;
    const unsigned short* wb1 = s_w + (size_t)(q1 * 16 + col) * WS_LD;
    const int u_ep = tid >> 5;          // 0..7  (and +8 for second pair)
    const int b_ep = tid & 31;
    float c0 = 0.f, c1 = 0.f;

    for (int t = 0; t < T_SEQ; ++t) {
        const unsigned short* hp = hs + (size_t)t * NB * HP + (size_t)(bh * 16 + col) * HP;
        // xg contributions are barrier-independent: issue early
        const s16x4 x0 = *(const s16x4*)&xg[((size_t)t * NJ + q0 * RW + wg * 16 + col) * NB
                                           + bh * 16 + quad * 4];
        const s16x4 x1 = *(const s16x4*)&xg[((size_t)t * NJ + q1 * RW + wg * 16 + col) * NB
                                           + bh * 16 + quad * 4];
        f32x4 A0 = {0.f, 0.f, 0.f, 0.f};
        f32x4 A1 = {0.f, 0.f, 0.f, 0.f};
#pragma unroll 16
        for (int kc = 0; kc < 32; ++kc) {
            int ko = kc * 32 + quad * 8;
            s16x8 a  = *(const s16x8*)&hp[ko];
            s16x8 b0 = *(const s16x8*)&wb0[ko];
            s16x8 b1 = *(const s16x8*)&wb1[ko];
            A0 = __builtin_amdgcn_mfma_f32_16x16x32_bf16(a, b0, A0, 0, 0, 0);
            A1 = __builtin_amdgcn_mfma_f32_16x16x32_bf16(a, b1, A1, 0, 0, 0);
        }
#pragma unroll
        for (int r = 0; r < 4; ++r) {
            s_g[(q0 * 16 + col) * 36 + bh * 16 + quad * 4 + r] = A0[r] + bf2f((unsigned short)x0[r]);
            s_g[(q1 * 16 + col) * 36 + bh * 16 + quad * 4 + r] = A1[r] + bf2f((unsigned short)x1[r]);
        }
        __syncthreads();
        // epilogue: 512 (u,b) pairs, 2 per thread; c-state in registers
        {
            float gi = s_g[(0 * 16 + u_ep) * 36 + b_ep];
            float gf = s_g[(1 * 16 + u_ep) * 36 + b_ep];
            float gg = s_g[(2 * 16 + u_ep) * 36 + b_ep];
            float go = s_g[(3 * 16 + u_ep) * 36 + b_ep];
            c0 = fsig(gf) * c0 + fsig(gi) * ftanh(gg);
            float h = fsig(go) * ftanh(c0);
            hs[((size_t)(t + 1) * NB + b_ep) * HP + wg * 16 + u_ep] = f2bf(h);
        }
        {
            int u2 = u_ep + 8;
            float gi = s_g[(0 * 16 + u2) * 36 + b_ep];
            float gf = s_g[(1 * 16 + u2) * 36 + b_ep];
            float gg = s_g[(2 * 16 + u2) * 36 + b_ep];
            float go = s_g[(3 * 16 + u2) * 36 + b_ep];
            c1 = fsig(gf) * c1 + fsig(gi) * ftanh(gg);
            float h = fsig(go) * ftanh(c1);
            hs[((size_t)(t + 1) * NB + b_ep) * HP + wg * 16 + u2] = f2bf(h);
        }
        if (t < T_SEQ - 1) gbar2(flags, (unsigned)(t + 2));
    }
}

// ---------------------------------------------------------------------------
// tag_kernel: tag_space + log_softmax over BATCH axis -> em[t][b][k] (f32)
// ---------------------------------------------------------------------------
__global__ __launch_bounds__(320) void tag_kernel(
    const unsigned short* __restrict__ hs, const float* __restrict__ lin_w,
    const float* __restrict__ lin_b, float* __restrict__ em)
{
    __shared__ float s_lin[NH * NK];
    __shared__ float s_ts[NB * NK];
    __shared__ float s_lse[NK];
    const int t = blockIdx.x, tid = threadIdx.x;
    for (int idx = tid; idx < NH * NK; idx += 320) {
        int e = idx / NK, k = idx - e * NK;
        s_lin[idx] = lin_w[(size_t)k * NH + e];
    }
    __syncthreads();
    if (tid < NB * NK) {
        int b = tid / NK, k = tid - b * NK;
        const unsigned short* hrow = hs + ((size_t)(t + 1) * NB + b) * HP;
        float acc = lin_b[k];
#pragma unroll 4
        for (int e = 0; e < NH; ++e)
            acc += bf2f(hrow[e]) * s_lin[e * NK + k];
        s_ts[b * NK + k] = acc;
    }
    __syncthreads();
    if (tid < NK) {
        float m = -1e30f;
        for (int b = 0; b < NB; ++b) m = fmaxf(m, s_ts[b * NK + tid]);
        float s = 0.f;
        for (int b = 0; b < NB; ++b) s += __expf(s_ts[b * NK + tid] - m);
        s_lse[tid] = m + __logf(s);
    }
    __syncthreads();
    if (tid < NB * NK) {
        int b = tid / NK, k = tid - b * NK;
        em[((size_t)t * NB + b) * NK + k] = s_ts[b * NK + k] - s_lse[k];
    }
}

// ---------------------------------------------------------------------------
// crf_kernel: numerator + alpha recursion + reduction -> out[0]
// ---------------------------------------------------------------------------
__global__ __launch_bounds__(320) void crf_kernel(
    const int* __restrict__ y, const float* __restrict__ em,
    const float* __restrict__ start_trans, const float* __restrict__ end_trans,
    const float* __restrict__ trans, float* __restrict__ out)
{
    __shared__ float s_trans[NK * NK];
    __shared__ float s_alpha[NB * NK];
    __shared__ float s_red[NB];
    const int tid = threadIdx.x;
    if (tid < NK * NK) s_trans[tid] = trans[tid];
    __syncthreads();

    float num = 0.f;
    if (tid < NB) {
        int b = tid, yp = y[b];
        num = start_trans[yp] + em[(size_t)b * NK + yp];
        for (int t = 1; t < T_SEQ; ++t) {
            int yc = y[t * NB + b];
            num += s_trans[yp * NK + yc] + em[((size_t)t * NB + b) * NK + yc];
            yp = yc;
        }
        num += end_trans[yp];
    }

    const int b = tid / NK, k = tid - (tid / NK) * NK;
    if (tid < NB * NK)
        s_alpha[tid] = start_trans[k] + em[(size_t)b * NK + k];
    __syncthreads();

    for (int t = 1; t < T_SEQ; ++t) {
        float nv = 0.f;
        if (tid < NB * NK) {
            float m = -1e30f;
#pragma unroll
            for (int i = 0; i < NK; ++i)
                m = fmaxf(m, s_alpha[b * NK + i] + s_trans[i * NK + k]);
            float s = 0.f;
#pragma unroll
            for (int i = 0; i < NK; ++i)
                s += __expf(s_alpha[b * NK + i] + s_trans[i * NK + k] - m);
            nv = em[((size_t)t * NB + b) * NK + k] + m + __logf(s);
        }
        __syncthreads();
        if (tid < NB * NK) s_alpha[tid] = nv;
        __syncthreads();
    }

    if (tid < NB) {
        float m = -1e30f;
        for (int k2 = 0; k2 < NK; ++k2)
            m = fmaxf(m, s_alpha[tid * NK + k2] + end_trans[k2]);
        float s = 0.f;
        for (int k2 = 0; k2 < NK; ++k2)
            s += __expf(s_alpha[tid * NK + k2] + end_trans[k2] - m);
        s_red[tid] = num - (m + __logf(s));
    }
    __syncthreads();
    if (tid == 0) {
        float tot = 0.f;
        for (int i = 0; i < NB; ++i) tot += s_red[i];
        out[0] = tot;
    }
}

// ---------------------------------------------------------------------------
extern "C" void kernel_launch(void* const* d_in, const int* in_sizes, int n_in,
                              void* d_out, int out_size, void* d_ws, size_t ws_size,
                              hipStream_t stream)
{
    const int*   x           = (const int*)d_in[0];
    const int*   y           = (const int*)d_in[1];
    const float* embed_w     = (const float*)d_in[2];
    const float* W_ih        = (const float*)d_in[3];
    const float* W_hh        = (const float*)d_in[4];
    const float* b_ih        = (const float*)d_in[5];
    const float* b_hh        = (const float*)d_in[6];
    const float* lin_w       = (const float*)d_in[7];
    const float* lin_b       = (const float*)d_in[8];
    const float* start_trans = (const float*)d_in[9];
    const float* end_trans   = (const float*)d_in[10];
    const float* trans       = (const float*)d_in[11];
    float* out = (float*)d_out;

    char* ws = (char*)d_ws;
    unsigned short* xg     = (unsigned short*)(ws);               // 51,609,600 B
    unsigned short* hs     = (unsigned short*)(ws + 51609600);    // 13,172,736 B
    float*          em     = (float*)(ws + 64782336);             //    230,400 B
    unsigned short* emb_bf = (unsigned short*)(ws + 65012736);    //  4,096,000 B
    unsigned short* wih_bf = (unsigned short*)(ws + 69108736);    //  2,580,480 B
    float*          biasg  = (float*)(ws + 71689216);             //     16,128 B
    unsigned*       flags  = (unsigned*)(ws + 71705344);          //      8,192 B

    prep_emb<<<dim3(T_SEQ), 256, 0, stream>>>(x, embed_w, emb_bf, flags);
    prep_w<<<dim3(63), 256, 0, stream>>>(W_ih, b_ih, b_hh, wih_bf, biasg);
    proj_kernel<<<dim3(63, T_SEQ), 256, 0, stream>>>(emb_bf, wih_bf, biasg, xg);

    const float* a0 = W_hh;
    const unsigned short* a1 = xg;
    unsigned short* a2 = hs;
    unsigned* a3 = flags;
    void* args[] = { (void*)&a0, (void*)&a1, (void*)&a2, (void*)&a3 };
    hipLaunchCooperativeKernel((const void*)lstm_kernel, dim3(63), dim3(256),
                               args, 0, stream);

    tag_kernel<<<dim3(T_SEQ), 320, 0, stream>>>(hs, lin_w, lin_b, em);
    crf_kernel<<<dim3(1), 320, 0, stream>>>(y, em, start_trans, end_trans, trans, out);
}